// Round 8
// baseline (720.634 us; speedup 1.0000x reference)
//
#include <hip/hip_runtime.h>
#include <hip/hip_fp16.h>

// Multi-level sparse hash encoding (instant-NGP style), forward only.
// B = 2^20 points, D=3, L=16 levels, E=2 features, tables (16, 16385, 2) f32.
//
// v9: FUSED single kernel. R6/R7 proved: two-phase kernel time ~91 us =
// phase1 ~55 (LDS-gather floor) + phase2 ~33 (pure BW, 201 MB) + gap; the
// ws round-trip exists only because one wg couldn't assemble full 128B
// output rows. This kernel can: each thread holds a point's FULL 16-level
// result in 16 half2 regs (levels loop fully unrolled -> static indexing),
// the 16 tables cycle through a double-buffered fp16 LDS pair (64 KB each),
// staging for level l+1 is register-prefetched (T14 split: global loads
// issued before level-l gathers, ds_writes after) so L2-served table reads
// (~1 us/level, tables fit each XCD's L2) hide under gathers (~1.3 us/level).
// Epilogue: in-LDS transpose -> fully coalesced float4 output stores.
// Deletes: ws write (67 MB) + ws read (67 MB) + second kernel launch.
// Per-CU floor: LDS pipe ~109k cyc ~= 45 us; VALU ~49k; HBM ~25 us.

typedef __attribute__((ext_vector_type(2))) float f32x2;

#define B_POINTS (1 << 20)
#define N_LEVELS 16
#define TAB_F2   16385                 // f32x2 rows per level in global emb
#define WG       1024
#define TILE     2048                  // points per wg (2 per thread)
#define NWG      (B_POINTS / TILE)     // 512
#define TPAD     17                    // transpose row pad (odd -> 2-way banks)

// compile-time level constants (levels loop is fully unrolled -> all fold)
constexpr int   kRES[N_LEVELS]  = {16, 20, 25, 32, 40, 50, 64, 80,
                                   101, 128, 161, 203, 256, 322, 406, 512};
constexpr float kHALF[N_LEVELS] = {8.f, 10.f, 12.5f, 16.f, 20.f, 25.f, 32.f, 40.f,
                                   50.5f, 64.f, 80.5f, 101.5f, 128.f, 161.f, 203.f, 256.f};
// rows used per level (direct: R^3, hashed: 16384; sentinel never gathered)
constexpr int   kROWS[N_LEVELS] = {4096, 8000, 15625, 16384, 16384, 16384, 16384, 16384,
                                   16384, 16384, 16384, 16384, 16384, 16384, 16384, 16384};

__device__ __forceinline__ unsigned pack_h2(const f32x2 v)
{
    __half2 h = __floats2half2_rn(v.x, v.y);   // .x = low
    return *reinterpret_cast<unsigned*>(&h);
}

// One level's 8-corner trilinear gather from a fp16 LDS table at tb.
// R/half/direct are compile-time constants at every call site (unrolled l).
__device__ __forceinline__ unsigned gather_lvl(const char* __restrict__ tb,
                                               float cx, float cy, float cz,
                                               const int R, const float half,
                                               const bool direct)
{
    const int   Rm1 = R - 1;
    const float hb  = half - 0.5f;
    const float xs0 = fmaf(cx, half, hb);
    const float xs1 = fmaf(cy, half, hb);
    const float xs2 = fmaf(cz, half, hb);
    const float fl0 = floorf(xs0), fl1 = floorf(xs1), fl2 = floorf(xs2);
    const float f0 = xs0 - fl0, f1 = xs1 - fl1, f2 = xs2 - fl2;
    const float g0 = 1.0f - f0, g1 = 1.0f - f1, g2 = 1.0f - f2;
    const int i0 = (int)fl0, i1 = (int)fl1, i2 = (int)fl2;

    // x in [-1,1) => i in [-1, R-1]: lower corner invalid only at i == -1,
    // upper only at i+1 == R -> one compare per weight factor.
    const float wx0 = (i0 >= 0)  ? g0 : 0.0f;
    const float wx1 = (i0 < Rm1) ? f0 : 0.0f;
    const float wy0 = (i1 >= 0)  ? g1 : 0.0f;
    const float wy1 = (i1 < Rm1) ? f1 : 0.0f;
    const float wz0 = (i2 >= 0)  ? g2 : 0.0f;
    const float wz1 = (i2 < Rm1) ? f2 : 0.0f;

    const f32x2 wyp = {wy0, wy1};
    const f32x2 wzp = {wz0, wz1};
    const f32x2 pA  = wyp * wx0;      // {pxy00, pxy01}
    const f32x2 pB  = wyp * wx1;      // {pxy10, pxy11}
    const f32x2 wA  = wzp * pA.x;     // {w0, w1}
    const f32x2 wB  = wzp * pA.y;     // {w2, w3}
    const f32x2 wC  = wzp * pB.x;     // {w4, w5}
    const f32x2 wD  = wzp * pB.y;     // {w6, w7}

    unsigned d0, d1, d2, d3, d4, d5, d6, d7;   // BYTE offsets into tb
    if (direct) {
        const int R4  = R * 4;         // constants after folding
        const int RR4 = R * R * 4;
        const int u0l = max(i0, 0), u0h = min(i0 + 1, Rm1);
        const int u1l = max(i1, 0), u1h = min(i1 + 1, Rm1);
        const int u2l = max(i2, 0), u2h = min(i2 + 1, Rm1);
        const int a0  = u0l * RR4,     a1  = u0h * RR4;
        const int b00 = a0 + u1l * R4, b01 = a0 + u1h * R4;
        const int b10 = a1 + u1l * R4, b11 = a1 + u1h * R4;
        const int zl  = u2l * 4,       zh  = u2h * 4;
        d0 = b00 + zl; d1 = b00 + zh; d2 = b01 + zl; d3 = b01 + zh;
        d4 = b10 + zl; d5 = b10 + zh; d6 = b11 + zl; d7 = b11 + zh;
    } else {
        // byte-domain hash: ((h & 16383) << 2) == (h*4) & (16383*4)
        const unsigned MB  = 16383u << 2;
        const unsigned hx0 = (unsigned)i0 << 2,                 hx1 = hx0 + 4u;
        const unsigned hy0 = (unsigned)i1 * (2654435761u * 4u), hy1 = hy0 + (2654435761u * 4u);
        const unsigned hzf = (unsigned)i2 * (805459861u * 4u);
        const unsigned hz0 = hzf & MB, hz1 = (hzf + (805459861u * 4u)) & MB;
        const unsigned t00 = (hx0 ^ hy0) & MB, t01 = (hx0 ^ hy1) & MB;
        const unsigned t10 = (hx1 ^ hy0) & MB, t11 = (hx1 ^ hy1) & MB;
        d0 = t00 ^ hz0; d1 = t00 ^ hz1; d2 = t01 ^ hz0; d3 = t01 ^ hz1;
        d4 = t10 ^ hz0; d5 = t10 ^ hz1; d6 = t11 ^ hz0; d7 = t11 ^ hz1;
    }

    const __half2 e0 = *(const __half2*)(tb + d0);
    const __half2 e1 = *(const __half2*)(tb + d1);
    const __half2 e2 = *(const __half2*)(tb + d2);
    const __half2 e3 = *(const __half2*)(tb + d3);
    const __half2 e4 = *(const __half2*)(tb + d4);
    const __half2 e5 = *(const __half2*)(tb + d5);
    const __half2 e6 = *(const __half2*)(tb + d6);
    const __half2 e7 = *(const __half2*)(tb + d7);

    f32x2 acc = {0.0f, 0.0f};
    const float2 q0 = __half22float2(e0);
    const float2 q1 = __half22float2(e1);
    const float2 q2 = __half22float2(e2);
    const float2 q3 = __half22float2(e3);
    const float2 q4 = __half22float2(e4);
    const float2 q5 = __half22float2(e5);
    const float2 q6 = __half22float2(e6);
    const float2 q7 = __half22float2(e7);
    acc += (f32x2){q0.x, q0.y} * wA.x;
    acc += (f32x2){q1.x, q1.y} * wA.y;
    acc += (f32x2){q2.x, q2.y} * wB.x;
    acc += (f32x2){q3.x, q3.y} * wB.y;
    acc += (f32x2){q4.x, q4.y} * wC.x;
    acc += (f32x2){q5.x, q5.y} * wC.y;
    acc += (f32x2){q6.x, q6.y} * wD.x;
    acc += (f32x2){q7.x, q7.y} * wD.y;

    __half2 hr = __floats2half2_rn(acc.x, acc.y);
    return *reinterpret_cast<unsigned*>(&hr);
}

__global__ __launch_bounds__(WG, 4)    // min 4 waves/SIMD -> VGPR cap 128
void hashenc_fused(const float* __restrict__ x,
                   const float* __restrict__ emb,
                   float4* __restrict__ out4)
{
    __shared__ unsigned sh[2 * 16384];   // 131072 B: double-buffered fp16 table
    const int t    = threadIdx.x;
    const int base = blockIdx.x * TILE;
    const int p0   = base + t;
    const int p1   = base + WG + t;

    const float3 v0 = ((const float3*)x)[p0];
    const float3 v1 = ((const float3*)x)[p1];

    unsigned res0[N_LEVELS];             // half2-packed result per level
    unsigned res1[N_LEVELS];             // (statically indexed: loop unrolled)

    // prologue: stage level 0 (4096 rows) into buf0
    {
        const f32x2* gt = (const f32x2*)emb;
#pragma unroll
        for (int i = 0; i < 4; ++i)
            sh[i * WG + t] = pack_h2(gt[i * WG + t]);
    }

#pragma unroll
    for (int l = 0; l < N_LEVELS; ++l) {
        __syncthreads();   // buf[l&1] staged; prior reads of buf[(l+1)&1] done
        const char* tb   = (const char*)(sh + (l & 1) * 16384);
        unsigned*   nbuf = sh + ((l + 1) & 1) * 16384;
        const int   nl   = l + 1;
        const f32x2* gt  = (const f32x2*)emb + (size_t)nl * TAB_F2;

        // T14 split, half A: issue next level's loads before gathering
        f32x2 sA[8];
        if (nl < N_LEVELS) {
#pragma unroll
            for (int i = 0; i < 8; ++i) {
                const int r = i * WG + t;
                if (i * WG < kROWS[nl])            // compile-time cull
                    if (r < kROWS[nl]) sA[i] = gt[r];
            }
        }

        res0[l] = gather_lvl(tb, v0.x, v0.y, v0.z, kRES[l], kHALF[l], l < 3);

        f32x2 sB[8];
        if (nl < N_LEVELS) {
#pragma unroll
            for (int i = 0; i < 8; ++i) {          // write half A
                const int r = i * WG + t;
                if (i * WG < kROWS[nl])
                    if (r < kROWS[nl]) nbuf[r] = pack_h2(sA[i]);
            }
#pragma unroll
            for (int i = 0; i < 8; ++i) {          // issue half B loads
                const int r = (8 + i) * WG + t;
                if ((8 + i) * WG < kROWS[nl])
                    if (r < kROWS[nl]) sB[i] = gt[r];
            }
        }

        res1[l] = gather_lvl(tb, v1.x, v1.y, v1.z, kRES[l], kHALF[l], l < 3);

        if (nl < N_LEVELS) {
#pragma unroll
            for (int i = 0; i < 8; ++i) {          // write half B
                const int r = (8 + i) * WG + t;
                if ((8 + i) * WG < kROWS[nl])
                    if (r < kROWS[nl]) nbuf[r] = pack_h2(sB[i]);
            }
        }
    }

    // ---- epilogue: in-LDS transpose -> coalesced float4 stores ----
    unsigned* tr = sh;                   // 1024*17 u32 = 69632 B (reused)
    const size_t obase = (size_t)base * 8;   // 8 float4 per point

    // pass 0: points [base, base+1024)
    __syncthreads();                     // level-15 gathers done
#pragma unroll
    for (int k = 0; k < N_LEVELS; ++k) tr[t * TPAD + k] = res0[k];
    __syncthreads();
#pragma unroll
    for (int j = 0; j < 8; ++j) {
        const int vIdx = j * WG + t;     // 0..8191
        const int pl = vIdx >> 3, lp = vIdx & 7;
        const __half2 ha = *(const __half2*)&tr[pl * TPAD + 2 * lp];
        const __half2 hb = *(const __half2*)&tr[pl * TPAD + 2 * lp + 1];
        const float2 fa = __half22float2(ha);
        const float2 fb = __half22float2(hb);
        out4[obase + vIdx] = make_float4(fa.x, fa.y, fb.x, fb.y);
    }

    // pass 1: points [base+1024, base+2048)
    __syncthreads();
#pragma unroll
    for (int k = 0; k < N_LEVELS; ++k) tr[t * TPAD + k] = res1[k];
    __syncthreads();
#pragma unroll
    for (int j = 0; j < 8; ++j) {
        const int vIdx = j * WG + t;
        const int pl = vIdx >> 3, lp = vIdx & 7;
        const __half2 ha = *(const __half2*)&tr[pl * TPAD + 2 * lp];
        const __half2 hb = *(const __half2*)&tr[pl * TPAD + 2 * lp + 1];
        const float2 fa = __half22float2(ha);
        const float2 fb = __half22float2(hb);
        out4[obase + 8192 + vIdx] = make_float4(fa.x, fa.y, fb.x, fb.y);
    }
}

extern "C" void kernel_launch(void* const* d_in, const int* in_sizes, int n_in,
                              void* d_out, int out_size, void* d_ws, size_t ws_size,
                              hipStream_t stream) {
    const float* x   = (const float*)d_in[0];   // (B, 3) f32
    const float* emb = (const float*)d_in[1];   // (16, 16385, 2) f32
    float4* out4 = (float4*)d_out;              // (B, 16, 2) f32

    hashenc_fused<<<NWG, WG, 0, stream>>>(x, emb, out4);
}

// Round 9
// 690.621 us; speedup vs baseline: 1.0435x; 1.0435x over previous
//
#include <hip/hip_runtime.h>
#include <hip/hip_fp16.h>

// Multi-level sparse hash encoding (instant-NGP style), forward only.
// B = 2^20 points, D=3, L=16 levels, E=2 features, tables (16, 16385, 2) f32.
//
// v10 = v9 (fused, correctness-verified) + spill fix.
// R8 diagnosis: compiler targeted 8 waves/EU (64-VGPR budget) despite the
// 131 KB LDS capping residency at 4 waves/EU -> res/staging arrays spilled
// to scratch (WRITE_SIZE 956 MB vs 134 MB real output; 616 us).
//  - amdgpu_waves_per_eu(4,4): pins allocator to the true occupancy ->
//    128-VGPR budget, no spills (est. peak liveness ~85).
//  - staging in 4 chunks of 4 rows (8 VGPRs live, was 16), T14-split
//    around the two per-level gathers; tail chunks hidden by 16-wave TLP.
// Structure (unchanged): each thread holds 2 points' full 16-level results
// in 32 half2-packed regs (level loop fully unrolled -> static indexing);
// 16 fp16 tables cycle through a double-buffered 64 KB LDS pair; epilogue
// transposes in LDS and stores fully-coalesced float4 rows. No workspace.

typedef __attribute__((ext_vector_type(2))) float f32x2;

#define B_POINTS (1 << 20)
#define N_LEVELS 16
#define TAB_F2   16385                 // f32x2 rows per level in global emb
#define WG       1024
#define TILE     2048                  // points per wg (2 per thread)
#define NWG      (B_POINTS / TILE)     // 512
#define TPAD     17                    // transpose row pad (odd -> 2-way banks)

// compile-time level constants (levels loop is fully unrolled -> all fold)
constexpr int   kRES[N_LEVELS]  = {16, 20, 25, 32, 40, 50, 64, 80,
                                   101, 128, 161, 203, 256, 322, 406, 512};
constexpr float kHALF[N_LEVELS] = {8.f, 10.f, 12.5f, 16.f, 20.f, 25.f, 32.f, 40.f,
                                   50.5f, 64.f, 80.5f, 101.5f, 128.f, 161.f, 203.f, 256.f};
// rows used per level (direct: R^3, hashed: 16384; sentinel never gathered)
constexpr int   kROWS[N_LEVELS] = {4096, 8000, 15625, 16384, 16384, 16384, 16384, 16384,
                                   16384, 16384, 16384, 16384, 16384, 16384, 16384, 16384};

__device__ __forceinline__ unsigned pack_h2(const f32x2 v)
{
    __half2 h = __floats2half2_rn(v.x, v.y);   // .x = low
    return *reinterpret_cast<unsigned*>(&h);
}

// One level's 8-corner trilinear gather from a fp16 LDS table at tb.
// R/half/direct are compile-time constants at every call site (unrolled l).
__device__ __forceinline__ unsigned gather_lvl(const char* __restrict__ tb,
                                               float cx, float cy, float cz,
                                               const int R, const float half,
                                               const bool direct)
{
    const int   Rm1 = R - 1;
    const float hb  = half - 0.5f;
    const float xs0 = fmaf(cx, half, hb);
    const float xs1 = fmaf(cy, half, hb);
    const float xs2 = fmaf(cz, half, hb);
    const float fl0 = floorf(xs0), fl1 = floorf(xs1), fl2 = floorf(xs2);
    const float f0 = xs0 - fl0, f1 = xs1 - fl1, f2 = xs2 - fl2;
    const float g0 = 1.0f - f0, g1 = 1.0f - f1, g2 = 1.0f - f2;
    const int i0 = (int)fl0, i1 = (int)fl1, i2 = (int)fl2;

    // x in [-1,1) => i in [-1, R-1]: lower corner invalid only at i == -1,
    // upper only at i+1 == R -> one compare per weight factor.
    const float wx0 = (i0 >= 0)  ? g0 : 0.0f;
    const float wx1 = (i0 < Rm1) ? f0 : 0.0f;
    const float wy0 = (i1 >= 0)  ? g1 : 0.0f;
    const float wy1 = (i1 < Rm1) ? f1 : 0.0f;
    const float wz0 = (i2 >= 0)  ? g2 : 0.0f;
    const float wz1 = (i2 < Rm1) ? f2 : 0.0f;

    const f32x2 wyp = {wy0, wy1};
    const f32x2 wzp = {wz0, wz1};
    const f32x2 pA  = wyp * wx0;      // {pxy00, pxy01}
    const f32x2 pB  = wyp * wx1;      // {pxy10, pxy11}
    const f32x2 wA  = wzp * pA.x;     // {w0, w1}
    const f32x2 wB  = wzp * pA.y;     // {w2, w3}
    const f32x2 wC  = wzp * pB.x;     // {w4, w5}
    const f32x2 wD  = wzp * pB.y;     // {w6, w7}

    unsigned d0, d1, d2, d3, d4, d5, d6, d7;   // BYTE offsets into tb
    if (direct) {
        const int R4  = R * 4;         // constants after folding
        const int RR4 = R * R * 4;
        const int u0l = max(i0, 0), u0h = min(i0 + 1, Rm1);
        const int u1l = max(i1, 0), u1h = min(i1 + 1, Rm1);
        const int u2l = max(i2, 0), u2h = min(i2 + 1, Rm1);
        const int a0  = u0l * RR4,     a1  = u0h * RR4;
        const int b00 = a0 + u1l * R4, b01 = a0 + u1h * R4;
        const int b10 = a1 + u1l * R4, b11 = a1 + u1h * R4;
        const int zl  = u2l * 4,       zh  = u2h * 4;
        d0 = b00 + zl; d1 = b00 + zh; d2 = b01 + zl; d3 = b01 + zh;
        d4 = b10 + zl; d5 = b10 + zh; d6 = b11 + zl; d7 = b11 + zh;
    } else {
        // byte-domain hash: ((h & 16383) << 2) == (h*4) & (16383*4)
        const unsigned MB  = 16383u << 2;
        const unsigned hx0 = (unsigned)i0 << 2,                 hx1 = hx0 + 4u;
        const unsigned hy0 = (unsigned)i1 * (2654435761u * 4u), hy1 = hy0 + (2654435761u * 4u);
        const unsigned hzf = (unsigned)i2 * (805459861u * 4u);
        const unsigned hz0 = hzf & MB, hz1 = (hzf + (805459861u * 4u)) & MB;
        const unsigned t00 = (hx0 ^ hy0) & MB, t01 = (hx0 ^ hy1) & MB;
        const unsigned t10 = (hx1 ^ hy0) & MB, t11 = (hx1 ^ hy1) & MB;
        d0 = t00 ^ hz0; d1 = t00 ^ hz1; d2 = t01 ^ hz0; d3 = t01 ^ hz1;
        d4 = t10 ^ hz0; d5 = t10 ^ hz1; d6 = t11 ^ hz0; d7 = t11 ^ hz1;
    }

    const __half2 e0 = *(const __half2*)(tb + d0);
    const __half2 e1 = *(const __half2*)(tb + d1);
    const __half2 e2 = *(const __half2*)(tb + d2);
    const __half2 e3 = *(const __half2*)(tb + d3);
    const __half2 e4 = *(const __half2*)(tb + d4);
    const __half2 e5 = *(const __half2*)(tb + d5);
    const __half2 e6 = *(const __half2*)(tb + d6);
    const __half2 e7 = *(const __half2*)(tb + d7);

    f32x2 acc = {0.0f, 0.0f};
    const float2 q0 = __half22float2(e0);
    const float2 q1 = __half22float2(e1);
    const float2 q2 = __half22float2(e2);
    const float2 q3 = __half22float2(e3);
    const float2 q4 = __half22float2(e4);
    const float2 q5 = __half22float2(e5);
    const float2 q6 = __half22float2(e6);
    const float2 q7 = __half22float2(e7);
    acc += (f32x2){q0.x, q0.y} * wA.x;
    acc += (f32x2){q1.x, q1.y} * wA.y;
    acc += (f32x2){q2.x, q2.y} * wB.x;
    acc += (f32x2){q3.x, q3.y} * wB.y;
    acc += (f32x2){q4.x, q4.y} * wC.x;
    acc += (f32x2){q5.x, q5.y} * wC.y;
    acc += (f32x2){q6.x, q6.y} * wD.x;
    acc += (f32x2){q7.x, q7.y} * wD.y;

    __half2 hr = __floats2half2_rn(acc.x, acc.y);
    return *reinterpret_cast<unsigned*>(&hr);
}

__global__ __launch_bounds__(WG)
__attribute__((amdgpu_waves_per_eu(4, 4)))   // LDS caps at 4 waves/EU anyway:
void hashenc_fused(const float* __restrict__ x,   // give allocator 128 VGPRs
                   const float* __restrict__ emb,
                   float4* __restrict__ out4)
{
    __shared__ unsigned sh[2 * 16384];   // 131072 B: double-buffered fp16 table
    const int t    = threadIdx.x;
    const int base = blockIdx.x * TILE;

    const float3 v0 = ((const float3*)x)[base + t];
    const float3 v1 = ((const float3*)x)[base + WG + t];

    unsigned res0[N_LEVELS];             // half2-packed result per level
    unsigned res1[N_LEVELS];             // (statically indexed: loop unrolled)

    // prologue: stage level 0 (4096 rows) into buf0
    {
        const f32x2* gt = (const f32x2*)emb;
#pragma unroll
        for (int i = 0; i < 4; ++i)
            sh[i * WG + t] = pack_h2(gt[i * WG + t]);
    }

#pragma unroll
    for (int l = 0; l < N_LEVELS; ++l) {
        __syncthreads();   // buf[l&1] staged; prior reads of buf[(l+1)&1] done
        const char* tb   = (const char*)(sh + (l & 1) * 16384);
        unsigned*   nbuf = sh + ((l + 1) & 1) * 16384;
        const bool  more = (l + 1 < N_LEVELS);
        const int   nlc  = more ? (l + 1) : 0;         // compile-time clamp
        const int   nrows = kROWS[nlc];
        const f32x2* gt  = (const f32x2*)emb + (size_t)nlc * TAB_F2;

        // staging chunk ci covers rows [ci*4096, ci*4096+4096)
        f32x2 s[4];                      // 8 VGPRs of staging liveness
#define STAGE_LOAD(ci)                                                     \
        if (more) {                                                        \
            _Pragma("unroll")                                              \
            for (int j = 0; j < 4; ++j) {                                  \
                const int r = (ci) * 4096 + j * WG + t;                    \
                if ((ci) * 4096 + j * WG < nrows)                          \
                    if (r < nrows) s[j] = gt[r];                           \
            }                                                              \
        }
#define STAGE_WRITE(ci)                                                    \
        if (more) {                                                        \
            _Pragma("unroll")                                              \
            for (int j = 0; j < 4; ++j) {                                  \
                const int r = (ci) * 4096 + j * WG + t;                    \
                if ((ci) * 4096 + j * WG < nrows)                          \
                    if (r < nrows) nbuf[r] = pack_h2(s[j]);                \
            }                                                              \
        }

        STAGE_LOAD(0)                    // issue loads; hide under gather 0
        res0[l] = gather_lvl(tb, v0.x, v0.y, v0.z, kRES[l], kHALF[l], l < 3);
        STAGE_WRITE(0)
        STAGE_LOAD(1)                    // hide under gather 1
        res1[l] = gather_lvl(tb, v1.x, v1.y, v1.z, kRES[l], kHALF[l], l < 3);
        STAGE_WRITE(1)
        STAGE_LOAD(2)                    // tail chunks: TLP (16 waves) hides
        STAGE_WRITE(2)
        STAGE_LOAD(3)
        STAGE_WRITE(3)
#undef STAGE_LOAD
#undef STAGE_WRITE
    }

    // ---- epilogue: in-LDS transpose -> coalesced float4 stores ----
    unsigned* tr = sh;                   // 1024*17 u32 = 69632 B (reused)
    const size_t obase = (size_t)base * 8;   // 8 float4 per point

    // pass 0: points [base, base+1024)
    __syncthreads();                     // level-15 gathers done
#pragma unroll
    for (int k = 0; k < N_LEVELS; ++k) tr[t * TPAD + k] = res0[k];
    __syncthreads();
#pragma unroll
    for (int j = 0; j < 8; ++j) {
        const int vIdx = j * WG + t;     // 0..8191
        const int pl = vIdx >> 3, lp = vIdx & 7;
        const __half2 ha = *(const __half2*)&tr[pl * TPAD + 2 * lp];
        const __half2 hb = *(const __half2*)&tr[pl * TPAD + 2 * lp + 1];
        const float2 fa = __half22float2(ha);
        const float2 fb = __half22float2(hb);
        out4[obase + vIdx] = make_float4(fa.x, fa.y, fb.x, fb.y);
    }

    // pass 1: points [base+1024, base+2048)
    __syncthreads();
#pragma unroll
    for (int k = 0; k < N_LEVELS; ++k) tr[t * TPAD + k] = res1[k];
    __syncthreads();
#pragma unroll
    for (int j = 0; j < 8; ++j) {
        const int vIdx = j * WG + t;
        const int pl = vIdx >> 3, lp = vIdx & 7;
        const __half2 ha = *(const __half2*)&tr[pl * TPAD + 2 * lp];
        const __half2 hb = *(const __half2*)&tr[pl * TPAD + 2 * lp + 1];
        const float2 fa = __half22float2(ha);
        const float2 fb = __half22float2(hb);
        out4[obase + 8192 + vIdx] = make_float4(fa.x, fa.y, fb.x, fb.y);
    }
}

extern "C" void kernel_launch(void* const* d_in, const int* in_sizes, int n_in,
                              void* d_out, int out_size, void* d_ws, size_t ws_size,
                              hipStream_t stream) {
    const float* x   = (const float*)d_in[0];   // (B, 3) f32
    const float* emb = (const float*)d_in[1];   // (16, 16385, 2) f32
    float4* out4 = (float4*)d_out;              // (B, 16, 2) f32

    hashenc_fused<<<NWG, WG, 0, stream>>>(x, emb, out4);
}

// Round 10
// 196.094 us; speedup vs baseline: 3.6749x; 3.5219x over previous
//
#include <hip/hip_runtime.h>
#include <hip/hip_fp16.h>

// Multi-level sparse hash encoding (instant-NGP style), forward only.
// B = 2^20 points, D=3, L=16 levels, E=2 features, tables (16, 16385, 2) f32.
//
// v11 = v8 REVERT (verified 196.5 us; best). The fused single-kernel line
// (v9/v10) is compiler-blocked: at WG=1024 the allocator pins 64 VGPRs
// (launch_bounds and amdgpu_waves_per_eu both ignored) -> ~1.5 KB/thread
// scratch churn, 597-616 us. Two-phase structure is at its composite floor:
//   Phase 1 (hashenc_lvl, ~55 us): one level per wg, fp16 LDS table,
//     2 wgs/CU (32 waves); random-gather LDS floor ~50 us (8192 wave
//     ds_read_b32/CU at ~1.6x bank serialization + VALU partial-hide).
//   Phase 2 (out_transpose, ~33 us): 201 MB coalesced = BW floor.
//   + ~105 us untouchable harness fill/poison traffic.
// Packed-VALU (R7) null; occupancy exhausted (R4); single-phase variants
// pin at ~100 us on the store-TA wall (R3-R5). Bench floor ~192 us.

typedef __attribute__((ext_vector_type(2))) float f32x2;

#define B_POINTS (1 << 20)
#define N_LEVELS 16
#define TAB_F2   16385                 // f32x2 rows per level in global emb
#define WG       1024

// phase 1
#define NWG      512                   // 2 wgs/CU
#define NCHUNK   (NWG / N_LEVELS)      // 32 point chunks
#define CHUNK    (B_POINTS / NCHUNK)   // 32768 points per wg
#define PPT      (CHUNK / WG)          // 32 points per thread
#define GRP      4                     // pipelined group size
#define NGRP     (PPT / GRP)           // 8 groups

// phase 2
#define T_WG     256
#define T_TILE   256                   // points per transpose wg
#define T_NWG    (B_POINTS / T_TILE)   // 4096

// floor(16 * gf^l) with gf = float32 exp chain (rounds above 2^(1/3)):
__constant__ int   cRES[N_LEVELS]  = {16, 20, 25, 32, 40, 50, 64, 80,
                                      101, 128, 161, 203, 256, 322, 406, 512};
__constant__ float cHALF[N_LEVELS] = {8.f, 10.f, 12.5f, 16.f, 20.f, 25.f, 32.f, 40.f,
                                      50.5f, 64.f, 80.5f, 101.5f, 128.f, 161.f, 203.f, 256.f};
// fallback kernel tables (rows used per level; LDS base within pair):
__constant__ int   cROWS[N_LEVELS] = {4096, 8000, 15625, 16384, 16384, 16384, 16384, 16384,
                                      16384, 16384, 16384, 16384, 16384, 16384, 16384, 16384};
__constant__ int   cBASE[N_LEVELS] = {0, 4096, 16384, 0, 0, 16384, 0, 16384,
                                      0, 16384, 0, 16384, 0, 16384, 0, 16384};

// ---------------------------------------------------------------- phase 1 --
__global__ __launch_bounds__(WG, 8)
void hashenc_lvl(const float* __restrict__ x,
                 const float* __restrict__ emb,
                 __half2* __restrict__ ws)
{
    __shared__ __half2 tab[16384];     // 65536 B — 2 wgs/CU, 32 waves

    // XCD swizzle: chunk c's 16 level-wgs all have bid % 8 == c % 8.
    const int bid = blockIdx.x;
    const int xcd = bid & 7;
    const int s   = bid >> 3;          // 0..63
    const int l   = s & 15;
    const int c   = ((s >> 4) << 3) | xcd;   // bijective: 0..31

    const int   R      = cRES[l];
    const int   Rm1    = R - 1;
    const float half   = cHALF[l];
    const float hb     = half - 0.5f;
    const bool  direct = (l < 3);
    const int   R4     = R * 4;        // byte strides in the half2 table
    const int   RR4    = R * R * 4;

    const f32x2* __restrict__ gtab = (const f32x2*)emb + (size_t)l * TAB_F2;
    const int t    = threadIdx.x;
    const int base = c * CHUNK + t;

    // first x group issued before staging (independent of LDS)
    float xa[GRP], xb[GRP], xcv[GRP];
#pragma unroll
    for (int j = 0; j < GRP; ++j) {
        const float3 v = ((const float3*)x)[base + j * WG];
        xa[j] = v.x; xb[j] = v.y; xcv[j] = v.z;
    }

    // ---- stage the level table into LDS, f32 -> fp16 (RNE) ----
#pragma unroll
    for (int j = 0; j < 16; ++j) {
        const f32x2 v = gtab[j * WG + t];
        __half2 h;
        h.x = __float2half_rn(v.x);
        h.y = __float2half_rn(v.y);
        tab[j * WG + t] = h;
    }
    __syncthreads();

    const char* tb = (const char*)tab;
    __half2* __restrict__ wsl = ws + (size_t)l * B_POINTS;

    for (int kg = 0; kg < NGRP; ++kg) {
        float ca[GRP], cb[GRP], cc[GRP];
#pragma unroll
        for (int j = 0; j < GRP; ++j) { ca[j] = xa[j]; cb[j] = xb[j]; cc[j] = xcv[j]; }

        if (kg + 1 < NGRP) {           // prefetch next group; hides under compute
#pragma unroll
            for (int j = 0; j < GRP; ++j) {
                const float3 v = ((const float3*)x)[base + (kg + 1) * (GRP * WG) + j * WG];
                xa[j] = v.x; xb[j] = v.y; xcv[j] = v.z;
            }
        }

#pragma unroll
        for (int j = 0; j < GRP; ++j) {
            const int p = base + kg * (GRP * WG) + j * WG;

            const float xs0 = fmaf(ca[j], half, hb);
            const float xs1 = fmaf(cb[j], half, hb);
            const float xs2 = fmaf(cc[j], half, hb);
            const float fl0 = floorf(xs0), fl1 = floorf(xs1), fl2 = floorf(xs2);
            const float f0 = xs0 - fl0, f1 = xs1 - fl1, f2 = xs2 - fl2;
            const float g0 = 1.0f - f0, g1 = 1.0f - f1, g2 = 1.0f - f2;
            const int i0 = (int)fl0, i1 = (int)fl1, i2 = (int)fl2;

            // x in [-1,1) => i in [-1, R-1]: one compare per weight factor.
            const float wx0 = (i0 >= 0)  ? g0 : 0.0f;
            const float wx1 = (i0 < Rm1) ? f0 : 0.0f;
            const float wy0 = (i1 >= 0)  ? g1 : 0.0f;
            const float wy1 = (i1 < Rm1) ? f1 : 0.0f;
            const float wz0 = (i2 >= 0)  ? g2 : 0.0f;
            const float wz1 = (i2 < Rm1) ? f2 : 0.0f;

            // packed weight products: 6 v_pk_mul_f32 replace 12 v_mul_f32
            const f32x2 wyp = {wy0, wy1};
            const f32x2 wzp = {wz0, wz1};
            const f32x2 pA  = wyp * wx0;      // {pxy00, pxy01}
            const f32x2 pB  = wyp * wx1;      // {pxy10, pxy11}
            const f32x2 wA  = wzp * pA.x;     // {w0, w1}
            const f32x2 wB  = wzp * pA.y;     // {w2, w3}
            const f32x2 wC  = wzp * pB.x;     // {w4, w5}
            const f32x2 wD  = wzp * pB.y;     // {w6, w7}

            unsigned d0, d1, d2, d3, d4, d5, d6, d7;   // BYTE offsets into tab
            if (direct) {
                const int u0l = max(i0, 0), u0h = min(i0 + 1, Rm1);
                const int u1l = max(i1, 0), u1h = min(i1 + 1, Rm1);
                const int u2l = max(i2, 0), u2h = min(i2 + 1, Rm1);
                const int a0  = u0l * RR4,     a1  = u0h * RR4;
                const int b00 = a0 + u1l * R4, b01 = a0 + u1h * R4;
                const int b10 = a1 + u1l * R4, b11 = a1 + u1h * R4;
                const int zl  = u2l * 4,       zh  = u2h * 4;
                d0 = b00 + zl; d1 = b00 + zh; d2 = b01 + zl; d3 = b01 + zh;
                d4 = b10 + zl; d5 = b10 + zh; d6 = b11 + zl; d7 = b11 + zh;
            } else {
                const unsigned MB  = 16383u << 2;
                const unsigned hx0 = (unsigned)i0 << 2,                 hx1 = hx0 + 4u;
                const unsigned hy0 = (unsigned)i1 * (2654435761u * 4u), hy1 = hy0 + (2654435761u * 4u);
                const unsigned hzf = (unsigned)i2 * (805459861u * 4u);
                const unsigned hz0 = hzf & MB, hz1 = (hzf + (805459861u * 4u)) & MB;
                const unsigned t00 = (hx0 ^ hy0) & MB, t01 = (hx0 ^ hy1) & MB;
                const unsigned t10 = (hx1 ^ hy0) & MB, t11 = (hx1 ^ hy1) & MB;
                d0 = t00 ^ hz0; d1 = t00 ^ hz1; d2 = t01 ^ hz0; d3 = t01 ^ hz1;
                d4 = t10 ^ hz0; d5 = t10 ^ hz1; d6 = t11 ^ hz0; d7 = t11 ^ hz1;
            }

            const __half2 e0 = *(const __half2*)(tb + d0);
            const __half2 e1 = *(const __half2*)(tb + d1);
            const __half2 e2 = *(const __half2*)(tb + d2);
            const __half2 e3 = *(const __half2*)(tb + d3);
            const __half2 e4 = *(const __half2*)(tb + d4);
            const __half2 e5 = *(const __half2*)(tb + d5);
            const __half2 e6 = *(const __half2*)(tb + d6);
            const __half2 e7 = *(const __half2*)(tb + d7);

            // packed accumulate: 8 v_pk_fma_f32 replace 16 v_fma_f32
            // (identical order/values to the scalar version).
            f32x2 acc = {0.0f, 0.0f};
            {
                const float2 q0 = __half22float2(e0);
                const float2 q1 = __half22float2(e1);
                const float2 q2 = __half22float2(e2);
                const float2 q3 = __half22float2(e3);
                const float2 q4 = __half22float2(e4);
                const float2 q5 = __half22float2(e5);
                const float2 q6 = __half22float2(e6);
                const float2 q7 = __half22float2(e7);
                acc += (f32x2){q0.x, q0.y} * wA.x;
                acc += (f32x2){q1.x, q1.y} * wA.y;
                acc += (f32x2){q2.x, q2.y} * wB.x;
                acc += (f32x2){q3.x, q3.y} * wB.y;
                acc += (f32x2){q4.x, q4.y} * wC.x;
                acc += (f32x2){q5.x, q5.y} * wC.y;
                acc += (f32x2){q6.x, q6.y} * wD.x;
                acc += (f32x2){q7.x, q7.y} * wD.y;
            }

            // ws[l][p] — 4B/lane, fully coalesced streaming store
            wsl[p] = __floats2half2_rn(acc.x, acc.y);
        }
    }
}

// ---------------------------------------------------------------- phase 2 --
// (16, B) half2  ->  (B, 16, 2) f32, tiled through LDS; both sides coalesced.
__global__ __launch_bounds__(T_WG)
void out_transpose(const __half2* __restrict__ ws, float4* __restrict__ out4)
{
    __shared__ unsigned lds[T_TILE * 17];   // half2 payloads, +1 pad per 16
    const int p0 = blockIdx.x * T_TILE;
    const int t  = threadIdx.x;

    // loads: 8B/lane (uint2 = 2 consecutive points of one level), coalesced
#pragma unroll
    for (int j = 0; j < (T_TILE * N_LEVELS / 2) / T_WG; ++j) {   // 8
        const int u   = j * T_WG + t;         // 0..2047
        const int l   = u >> 7;               // 128 point-pairs per level
        const int pl2 = u & 127;
        const uint2 w2 = ((const uint2*)(ws + (size_t)l * B_POINTS + p0))[pl2];
        lds[(2 * pl2)     * 17 + l] = w2.x;
        lds[(2 * pl2 + 1) * 17 + l] = w2.y;
    }
    __syncthreads();

    // stores: 16B/lane, consecutive float4s -> full-line coalesced
#pragma unroll
    for (int j = 0; j < (T_TILE * 8) / T_WG; ++j) {              // 8
        const int v  = j * T_WG + t;          // 0..2047
        const int pl = v >> 3, lp = v & 7;
        const __half2 ha = *(const __half2*)&lds[pl * 17 + 2 * lp];
        const __half2 hb = *(const __half2*)&lds[pl * 17 + 2 * lp + 1];
        const float2 fa = __half22float2(ha);
        const float2 fb = __half22float2(hb);
        out4[(size_t)p0 * 8 + v] = make_float4(fa.x, fa.y, fb.x, fb.y);
    }
}

// ------------------------------------------------- fallback (v6, verified) --
__device__ __forceinline__ void level_feat(const char* __restrict__ tb,
                                           float cx, float cy, float cz,
                                           int R, int Rm1, float half, float hb,
                                           bool direct, unsigned base4,
                                           float& acc0, float& acc1)
{
    const float xs0 = fmaf(cx, half, hb);
    const float xs1 = fmaf(cy, half, hb);
    const float xs2 = fmaf(cz, half, hb);
    const float fl0 = floorf(xs0), fl1 = floorf(xs1), fl2 = floorf(xs2);
    const float f0 = xs0 - fl0, f1 = xs1 - fl1, f2 = xs2 - fl2;
    const float g0 = 1.0f - f0, g1 = 1.0f - f1, g2 = 1.0f - f2;
    const int i0 = (int)fl0, i1 = (int)fl1, i2 = (int)fl2;
    const float wx0 = (i0 >= 0)  ? g0 : 0.0f;
    const float wx1 = (i0 < Rm1) ? f0 : 0.0f;
    const float wy0 = (i1 >= 0)  ? g1 : 0.0f;
    const float wy1 = (i1 < Rm1) ? f1 : 0.0f;
    const float wz0 = (i2 >= 0)  ? g2 : 0.0f;
    const float wz1 = (i2 < Rm1) ? f2 : 0.0f;
    const float pxy00 = wx0 * wy0, pxy01 = wx0 * wy1;
    const float pxy10 = wx1 * wy0, pxy11 = wx1 * wy1;
    const float w0 = pxy00 * wz0, w1 = pxy00 * wz1;
    const float w2 = pxy01 * wz0, w3 = pxy01 * wz1;
    const float w4 = pxy10 * wz0, w5 = pxy10 * wz1;
    const float w6 = pxy11 * wz0, w7 = pxy11 * wz1;
    unsigned d0, d1, d2, d3, d4, d5, d6, d7;
    if (direct) {
        const int R4  = R * 4;
        const int RR4 = R * R * 4;
        const int u0l = max(i0, 0), u0h = min(i0 + 1, Rm1);
        const int u1l = max(i1, 0), u1h = min(i1 + 1, Rm1);
        const int u2l = max(i2, 0), u2h = min(i2 + 1, Rm1);
        const int a0  = u0l * RR4 + (int)base4, a1 = u0h * RR4 + (int)base4;
        const int b00 = a0 + u1l * R4, b01 = a0 + u1h * R4;
        const int b10 = a1 + u1l * R4, b11 = a1 + u1h * R4;
        const int zl  = u2l * 4,       zh  = u2h * 4;
        d0 = b00 + zl; d1 = b00 + zh; d2 = b01 + zl; d3 = b01 + zh;
        d4 = b10 + zl; d5 = b10 + zh; d6 = b11 + zl; d7 = b11 + zh;
    } else {
        const unsigned MB  = 16383u << 2;
        const unsigned hx0 = (unsigned)i0 << 2,                 hx1 = hx0 + 4u;
        const unsigned hy0 = (unsigned)i1 * (2654435761u * 4u), hy1 = hy0 + (2654435761u * 4u);
        const unsigned hzf = (unsigned)i2 * (805459861u * 4u);
        const unsigned hz0 = (hzf & MB) | base4;
        const unsigned hz1 = ((hzf + (805459861u * 4u)) & MB) | base4;
        const unsigned t00 = (hx0 ^ hy0) & MB, t01 = (hx0 ^ hy1) & MB;
        const unsigned t10 = (hx1 ^ hy0) & MB, t11 = (hx1 ^ hy1) & MB;
        d0 = t00 ^ hz0; d1 = t00 ^ hz1; d2 = t01 ^ hz0; d3 = t01 ^ hz1;
        d4 = t10 ^ hz0; d5 = t10 ^ hz1; d6 = t11 ^ hz0; d7 = t11 ^ hz1;
    }
    const __half2 e0 = *(const __half2*)(tb + d0);
    const __half2 e1 = *(const __half2*)(tb + d1);
    const __half2 e2 = *(const __half2*)(tb + d2);
    const __half2 e3 = *(const __half2*)(tb + d3);
    const __half2 e4 = *(const __half2*)(tb + d4);
    const __half2 e5 = *(const __half2*)(tb + d5);
    const __half2 e6 = *(const __half2*)(tb + d6);
    const __half2 e7 = *(const __half2*)(tb + d7);
    acc0 = 0.0f; acc1 = 0.0f;
    acc0 = fmaf(__low2float(e0),  w0, acc0); acc1 = fmaf(__high2float(e0), w0, acc1);
    acc0 = fmaf(__low2float(e1),  w1, acc0); acc1 = fmaf(__high2float(e1), w1, acc1);
    acc0 = fmaf(__low2float(e2),  w2, acc0); acc1 = fmaf(__high2float(e2), w2, acc1);
    acc0 = fmaf(__low2float(e3),  w3, acc0); acc1 = fmaf(__high2float(e3), w3, acc1);
    acc0 = fmaf(__low2float(e4),  w4, acc0); acc1 = fmaf(__high2float(e4), w4, acc1);
    acc0 = fmaf(__low2float(e5),  w5, acc0); acc1 = fmaf(__high2float(e5), w5, acc1);
    acc0 = fmaf(__low2float(e6),  w6, acc0); acc1 = fmaf(__high2float(e6), w6, acc1);
    acc0 = fmaf(__low2float(e7),  w7, acc0); acc1 = fmaf(__high2float(e7), w7, acc1);
}

__device__ __forceinline__ void stage_level(__half2* __restrict__ tab,
                                            const f32x2* __restrict__ src,
                                            int rows, int obase, int t)
{
    for (int r0 = 0; r0 < rows; r0 += 4 * WG) {
        f32x2 v[4];
#pragma unroll
        for (int u = 0; u < 4; ++u) {
            const int r = r0 + u * WG + t;
            if (r < rows) v[u] = src[r];
        }
#pragma unroll
        for (int u = 0; u < 4; ++u) {
            const int r = r0 + u * WG + t;
            if (r < rows) {
                __half2 h;
                h.x = __float2half_rn(v[u].x);
                h.y = __float2half_rn(v[u].y);
                tab[obase + r] = h;
            }
        }
    }
}

__global__ __launch_bounds__(WG, 4)
void hashenc_pair(const float* __restrict__ x,
                  const float* __restrict__ emb,
                  float* __restrict__ out)
{
    __shared__ __half2 tab[32768];
    const int bid = blockIdx.x;
    const int xcd = bid & 7;
    const int s   = bid >> 3;
    const int m   = s & 7;
    const int c   = ((s >> 3) << 3) | xcd;
    const int lA = 2 * m, lB = 2 * m + 1;
    const int   RA = cRES[lA],  RB = cRES[lB];
    const int   RmA = RA - 1,   RmB = RB - 1;
    const float hA = cHALF[lA], hB = cHALF[lB];
    const float bA = hA - 0.5f, bB = hB - 0.5f;
    const bool  dA = (lA < 3),  dB = (lB < 3);
    const unsigned baseA = (unsigned)cBASE[lA] * 4u;
    const unsigned baseB = (unsigned)cBASE[lB] * 4u;
    const int t    = threadIdx.x;
    const int base = c * (B_POINTS / 32) + t;
    float xa[GRP], xb[GRP], xcv[GRP];
#pragma unroll
    for (int j = 0; j < GRP; ++j) {
        const float3 v = ((const float3*)x)[base + j * WG];
        xa[j] = v.x; xb[j] = v.y; xcv[j] = v.z;
    }
    stage_level(tab, (const f32x2*)emb + (size_t)lA * TAB_F2, cROWS[lA], cBASE[lA], t);
    stage_level(tab, (const f32x2*)emb + (size_t)lB * TAB_F2, cROWS[lB], cBASE[lB], t);
    __syncthreads();
    const char* tb = (const char*)tab;
    for (int kg = 0; kg < NGRP; ++kg) {
        float ca[GRP], cb[GRP], cc[GRP];
#pragma unroll
        for (int j = 0; j < GRP; ++j) { ca[j] = xa[j]; cb[j] = xb[j]; cc[j] = xcv[j]; }
        if (kg + 1 < NGRP) {
#pragma unroll
            for (int j = 0; j < GRP; ++j) {
                const float3 v = ((const float3*)x)[base + (kg + 1) * (GRP * WG) + j * WG];
                xa[j] = v.x; xb[j] = v.y; xcv[j] = v.z;
            }
        }
#pragma unroll
        for (int j = 0; j < GRP; ++j) {
            const int p = base + kg * (GRP * WG) + j * WG;
            float a0, a1, b0, b1;
            level_feat(tb, ca[j], cb[j], cc[j], RA, RmA, hA, bA, dA, baseA, a0, a1);
            level_feat(tb, ca[j], cb[j], cc[j], RB, RmB, hB, bB, dB, baseB, b0, b1);
            ((float4*)out)[(size_t)p * 8 + m] = make_float4(a0, a1, b0, b1);
        }
    }
}

// ---------------------------------------------------------------- launch ---
extern "C" void kernel_launch(void* const* d_in, const int* in_sizes, int n_in,
                              void* d_out, int out_size, void* d_ws, size_t ws_size,
                              hipStream_t stream) {
    const float* x   = (const float*)d_in[0];   // (B, 3) f32
    const float* emb = (const float*)d_in[1];   // (16, 16385, 2) f32
    float* out = (float*)d_out;                 // (B, 16, 2) f32

    const size_t ws_need = (size_t)N_LEVELS * B_POINTS * sizeof(__half2); // 64 MiB
    if (d_ws != nullptr && ws_size >= ws_need) {
        __half2* ws = (__half2*)d_ws;
        hashenc_lvl<<<NWG, WG, 0, stream>>>(x, emb, ws);
        out_transpose<<<T_NWG, T_WG, 0, stream>>>(ws, (float4*)out);
    } else {
        hashenc_pair<<<256, WG, 0, stream>>>(x, emb, out);
    }
}